// Round 4
// baseline (646.104 us; speedup 1.0000x reference)
//
#include <hip/hip_runtime.h>
#include <hip/hip_bf16.h>
#include <math.h>

#define L_SEQ 64
#define NB    128
#define EMBD  512
#define HID   256
#define G4    1024      // 4*HID
#define NCOL  2048      // 2 dirs * 4H
#define DDIM  512       // 2*HID
#define MS    (L_SEQ*NB)   // 8192 rows per sentence
#define MTOT  (2*MS)       // 16384 combined rows

typedef __bf16 bf16_t;
typedef bf16_t bf16x4 __attribute__((ext_vector_type(4)));
typedef bf16_t bf16x8 __attribute__((ext_vector_type(8)));
typedef float  floatx4 __attribute__((ext_vector_type(4)));
typedef float  floatx8 __attribute__((ext_vector_type(8)));

__device__ __forceinline__ bf16x8 cvt_bf16x8(floatx8 v) {
    bf16x8 r;
    r[0]=(bf16_t)v[0]; r[1]=(bf16_t)v[1]; r[2]=(bf16_t)v[2]; r[3]=(bf16_t)v[3];
    r[4]=(bf16_t)v[4]; r[5]=(bf16_t)v[5]; r[6]=(bf16_t)v[6]; r[7]=(bf16_t)v[7];
    return r;
}

__device__ __forceinline__ void gload_lds16(const bf16_t* g, bf16_t* l) {
    __builtin_amdgcn_global_load_lds(
        (const __attribute__((address_space(1))) unsigned int*)(g),
        (__attribute__((address_space(3))) unsigned int*)(l), 16, 0, 0);
}

__device__ __forceinline__ float fsigmoid(float x) {
    return __builtin_amdgcn_rcpf(1.0f + __expf(-x));
}
__device__ __forceinline__ float ftanh(float x) {
    return 1.0f - 2.0f * __builtin_amdgcn_rcpf(__expf(2.0f*x) + 1.0f);
}

// Raw workgroup barrier: drain LDS ops only (h ping-pong visibility), skip the
// vmcnt(0) store-ack drain __syncthreads would force.
#define LDS_BARRIER() asm volatile("s_waitcnt lgkmcnt(0)\n\ts_barrier" ::: "memory")

// ---------------------------------------------------------------------------
// k_pack_w: merged weight/bias packs (unchanged from R2)
// ---------------------------------------------------------------------------
__global__ __launch_bounds__(256) void k_pack_w(
    const float* __restrict__ wih_f, const float* __restrict__ wih_b,
    const float* __restrict__ whh_f, const float* __restrict__ whh_b,
    const float* __restrict__ bih_f, const float* __restrict__ bhh_f,
    const float* __restrict__ bih_b, const float* __restrict__ bhh_b,
    bf16_t* __restrict__ B, bf16_t* __restrict__ whhB,
    float* __restrict__ bias)
{
    int gid = blockIdx.x*256 + threadIdx.x;
    if (gid < 131072) {                       // wih pack: 2048 rows x 8 vec8
        int n  = gid >> 6;
        int k8 = (gid & 63) * 8;
        const float* src = (n >= 1024) ? (wih_b + (size_t)(n-1024)*EMBD)
                                       : (wih_f + (size_t)n*EMBD);
        *(bf16x8*)(B + (size_t)n*EMBD + k8) = cvt_bf16x8(*(const floatx8*)(src + k8));
    } else if (gid < 196608) {                // whh pack: 2048 rows x 4 vec8
        int g2 = gid - 131072;
        int r2 = g2 >> 5;
        int k8 = (g2 & 31) * 8;
        const float* src = (r2 >= 1024) ? (whh_b + (size_t)(r2-1024)*HID)
                                        : (whh_f + (size_t)r2*HID);
        *(bf16x8*)(whhB + (size_t)r2*HID + k8) = cvt_bf16x8(*(const floatx8*)(src + k8));
    } else {                                  // bias: 2048 scalars
        int n = gid - 196608;
        bias[n] = (n >= 1024) ? (bih_b[n-1024] + bhh_b[n-1024])
                              : (bih_f[n] + bhh_f[n]);
    }
}

// ---------------------------------------------------------------------------
// k_embgemm: fused emb-gather + xg GEMM (replaces k_pack_a + xg_gemm4).
//  256 blocks x 512 thr. Block owns A-panel = 64 token rows (gathered from
//  emb once, f32->bf16, staged into LDS with 16B-chunk XOR swizzle
//  c' = c ^ (row&7): reg-staged ds_write + identical XOR on the af read
//  -> both-sides-consistent, af row-stride 1KB conflict broken to ~2-way).
//  Then 4 N-passes of 512 cols x 16 K-iters: B staged per-iter via
//  global_load_lds (m97 2-barrier pattern), 8 waves each own a 64-col slab.
//  Per-output MFMA K-chain identical to xg_gemm4 -> xgT bitwise identical.
//  Eliminates: A buffer write (17MB), 16x A re-read (268MB L3), one launch.
//  Epilogue: same per-chunk transposed bf16 store:
//   xgT[(((s2*8 + ch)*64 + l)*1024 + gcol)*16 + bi]
// ---------------------------------------------------------------------------
__global__
__attribute__((amdgpu_flat_work_group_size(512, 512)))
void k_embgemm(const int* __restrict__ t1, const int* __restrict__ t2,
               const float* __restrict__ emb,
               const bf16_t* __restrict__ Bw, const float* __restrict__ bias,
               bf16_t* __restrict__ xgT)
{
    extern __shared__ char smem[];
    bf16_t* Al = (bf16_t*)smem;            // [64 rows][512] swizzled = 64 KB
    bf16_t* Bs = (bf16_t*)(smem + 65536);  // [512 cols][32 k]       = 32 KB

    const int tid  = threadIdx.x;
    const int wv   = tid >> 6;             // 0..7
    const int lane = tid & 63;
    const int l15  = lane & 15;
    const int quad = lane >> 4;
    const int blk  = blockIdx.x;           // 0..255
    const int m0   = blk * 64;

    // ---- A gather: 64 emb rows -> bf16 LDS, XOR-swizzled 16B chunks
    {
        const int rw   = tid >> 3;         // 0..63 local row
        const int c0   = tid & 7;          // chunk lane
        const int grow = m0 + rw;
        const int tok  = (grow < MS) ? t1[grow] : t2[grow - MS];
        const float* er = emb + (size_t)tok*EMBD;
#pragma unroll
        for (int i = 0; i < 8; ++i) {
            const int c  = c0 + i*8;       // chunk 0..63 (8 elems each)
            floatx8 v = *(const floatx8*)(er + c*8);
            const int cs = c ^ (rw & 7);
            *(bf16x8*)(Al + rw*512 + cs*8) = cvt_bf16x8(v);
        }
    }
    __syncthreads();

    const int sent = m0 >> 13;
    const int l    = (m0 >> 7) & 63;
    const int chb  = (blk & 1) * 4;

    for (int p = 0; p < 4; ++p) {          // N-pass: cols p*512 .. +511
        float biasv[4];
#pragma unroll
        for (int ni = 0; ni < 4; ++ni)
            biasv[ni] = bias[p*512 + wv*64 + ni*16 + l15];

        floatx4 acc[4][4] = {};            // [mi][ni]
        for (int kk = 0; kk < 16; ++kk) {
            // stage B tile: 512 cols x 32 k (m97 pattern, linear dest)
#pragma unroll
            for (int it = 0; it < 4; ++it) {
                const int idx = it*512 + tid;
                const int col = idx >> 2;
                const int k8  = (idx & 3) * 8;
                gload_lds16(Bw + (size_t)(p*512 + col)*EMBD + kk*32 + k8,
                            Bs + (size_t)(it*512 + wv*64)*8);
            }
            __syncthreads();

            bf16x8 a[4], b[4];
#pragma unroll
            for (int mi = 0; mi < 4; ++mi) {
                const int arow = mi*16 + l15;
                a[mi] = *(const bf16x8*)(Al + arow*512
                                         + (((kk*4 + quad) ^ (arow & 7))*8));
            }
#pragma unroll
            for (int ni = 0; ni < 4; ++ni)
                b[ni] = *(const bf16x8*)(Bs + (wv*64 + ni*16 + l15)*32 + quad*8);
#pragma unroll
            for (int mi = 0; mi < 4; ++mi)
#pragma unroll
                for (int ni = 0; ni < 4; ++ni)
                    acc[mi][ni] = __builtin_amdgcn_mfma_f32_16x16x32_bf16(
                                      a[mi], b[ni], acc[mi][ni], 0, 0, 0);
            __syncthreads();
        }

        // epilogue for this pass
        const int s2 = sent*2 + (p >> 1);
#pragma unroll
        for (int mi = 0; mi < 4; ++mi)
#pragma unroll
            for (int ni = 0; ni < 4; ++ni) {
                const int gcol = (p & 1)*512 + wv*64 + ni*16 + l15;
                const int ch   = chb + mi;
                bf16x4 v;
#pragma unroll
                for (int r = 0; r < 4; ++r)
                    v[r] = (bf16_t)(acc[mi][ni][r] + biasv[ni]);
                *(bf16x4*)(xgT + ((size_t)((s2*8 + ch)*64 + l)*1024 + gcol)*16
                           + quad*4) = v;
            }
    }
}

// ---------------------------------------------------------------------------
// LSTM scan v8 (unchanged — best known, 363us; pipe-sum/latency bound on its
// 32 CUs, weight slab 512KB > VGPR+LDS makes the ks6/7 stream irreducible,
// cross-block splits are dead per v9).
// ---------------------------------------------------------------------------
__global__
__attribute__((amdgpu_flat_work_group_size(1024, 1024), amdgpu_waves_per_eu(4, 4)))
void lstm_scan8(
    const bf16_t* __restrict__ whhB,   // [2][1024][256] bf16
    const bf16_t* __restrict__ xgT,    // per-chunk layout
    float* __restrict__ o1, float* __restrict__ o2)
{
    extern __shared__ char smem[];
    bf16_t* hb = (bf16_t*)smem;              // 2 frames x 4096 bf16 = 16 KB
    bf16_t* BL = (bf16_t*)(smem + 16384);    // 128 frags x 512 bf16 = 128 KB

    const int tid  = threadIdx.x;
    const int wv   = tid >> 6;            // 0..15
    const int lane = tid & 63;
    const int l15  = lane & 15;
    const int quad = lane >> 4;
    const int s2   = blockIdx.y;          // sent*2 + dr
    const int sent = s2 >> 1;
    const int dr   = s2 & 1;
    const int chunk= blockIdx.x;
    const int b0   = chunk * 16;
    float* o = sent ? o2 : o1;
    const bf16_t* bb = whhB + (size_t)dr * (1024*HID);

    // ---- LDS weight preload: ks 4,5 for all 4 gates of this wave's unit slice
#pragma unroll
    for (int g = 0; g < 4; ++g) {
        const int col = g*256 + wv*16 + l15;
#pragma unroll
        for (int ksl = 0; ksl < 2; ++ksl)
            gload_lds16(bb + (size_t)col*HID + (4+ksl)*32 + quad*8,
                        BL + (size_t)((wv*4 + g)*2 + ksl)*512);
    }

    // ---- VGPR weights ks0..3 — volatile loads: no rematerialization
    bf16x8 bwc[4][4];
#pragma unroll
    for (int g = 0; g < 4; ++g) {
        const bf16_t* cp = bb + (size_t)(g*256 + wv*16 + l15)*HID + quad*8;
#pragma unroll
        for (int ks = 0; ks < 4; ++ks)
            bwc[g][ks] = *(const volatile bf16x8*)(cp + ks*32);
    }

    // zero h frame 0 (legacy safety; frame 0 is never read before first write)
    for (int i = tid; i < 4096; i += 1024) hb[i] = (bf16_t)0.0f;
    __syncthreads();   // full drain once (also covers global_load_lds)

    float cst[4] = {};
    int pp = 0;

    for (int t = 0; t < L_SEQ; ++t) {
        const int lt = dr ? (L_SEQ-1-t) : t;
        asm volatile("" ::: "memory");   // keep in-loop loads in-loop

        // xg for THIS step: issued at top, consumed in epilogue — full MFMA
        // phase of slack to cover L2/L3 latency.
        bf16x4 xvc[4];
        {
            const bf16_t* xp = xgT + (size_t)((s2*8 + chunk)*64 + lt)*16384;
#pragma unroll
            for (int g = 0; g < 4; ++g)
                xvc[g] = *(const bf16x4*)(xp + (size_t)(g*256 + wv*16 + l15)*16
                                          + quad*4);
        }

        floatx4 acc[4] = {};
        if (t > 0) {
            // streamed weight buffer (single 16-reg buffer, used twice)
            bf16x8 sb[4];
#pragma unroll
            for (int g = 0; g < 4; ++g) {
                const bf16_t* cp = bb + (size_t)(g*256 + wv*16 + l15)*HID;
                sb[g] = *(const bf16x8*)(cp + 6*32 + quad*8);
            }

            const bf16_t* fr = hb + pp*4096;
            // ks0..3: VGPR weights
#pragma unroll
            for (int ks = 0; ks < 4; ++ks) {
                bf16x8 af = *(const bf16x8*)(fr + ((ks*4 + quad)*16 + l15)*8);
#pragma unroll
                for (int g = 0; g < 4; ++g)
                    acc[g] = __builtin_amdgcn_mfma_f32_16x16x32_bf16(
                                 af, bwc[g][ks], acc[g], 0, 0, 0);
            }
            // ks6: streamed batch 1 (issued at step top, latency covered)
            {
                bf16x8 af6 = *(const bf16x8*)(fr + ((6*4 + quad)*16 + l15)*8);
#pragma unroll
                for (int g = 0; g < 4; ++g)
                    acc[g] = __builtin_amdgcn_mfma_f32_16x16x32_bf16(
                                 af6, sb[g], acc[g], 0, 0, 0);
            }
            // reissue stream buffer for ks7; ks4,5 (LDS) hide its L2 latency
#pragma unroll
            for (int g = 0; g < 4; ++g) {
                const bf16_t* cp = bb + (size_t)(g*256 + wv*16 + l15)*HID;
                sb[g] = *(const bf16x8*)(cp + 7*32 + quad*8);
            }
            // ks4,5: LDS weights
#pragma unroll
            for (int ksl = 0; ksl < 2; ++ksl) {
                bf16x8 af = *(const bf16x8*)(fr + (((4+ksl)*4 + quad)*16 + l15)*8);
#pragma unroll
                for (int g = 0; g < 4; ++g) {
                    bf16x8 bl = *(const bf16x8*)(BL + (size_t)((wv*4 + g)*2 + ksl)*512
                                                 + lane*8);
                    acc[g] = __builtin_amdgcn_mfma_f32_16x16x32_bf16(
                                 af, bl, acc[g], 0, 0, 0);
                }
            }
            // ks7: streamed batch 2
            {
                bf16x8 af7 = *(const bf16x8*)(fr + ((7*4 + quad)*16 + l15)*8);
#pragma unroll
                for (int g = 0; g < 4; ++g)
                    acc[g] = __builtin_amdgcn_mfma_f32_16x16x32_bf16(
                                 af7, sb[g], acc[g], 0, 0, 0);
            }
        }

        // epilogue: rows m = quad*4+r, unit j = wv*16 + l15
        bf16_t* fw = hb + (pp^1)*4096;
        const int j = wv*16 + l15;
        float* orow = o + (size_t)(lt*NB + b0)*DDIM + dr*HID + j;
#pragma unroll
        for (int r = 0; r < 4; ++r) {
            const int m = quad*4 + r;
            float gi = acc[0][r] + (float)xvc[0][r];
            float gf = acc[1][r] + (float)xvc[1][r];
            float gg = acc[2][r] + (float)xvc[2][r];
            float go = acc[3][r] + (float)xvc[3][r];
            float cv = fsigmoid(gf)*cst[r] + fsigmoid(gi)*ftanh(gg);
            cst[r] = cv;
            float hv = fsigmoid(go)*ftanh(cv);
            orow[(size_t)m*DDIM] = hv;
            fw[((j >> 3)*16 + m)*8 + (j & 7)] = (bf16_t)hv;
        }
        LDS_BARRIER();
        pp ^= 1;
    }
}

// ---------------------------------------------------------------------------
// attention + sim with fused mp1 (unchanged from R2)
// ---------------------------------------------------------------------------
__global__ __launch_bounds__(256) void k_att(const float* __restrict__ o1,
                                             const float* __restrict__ o2,
                                             float* __restrict__ sim)
{
    const int b   = blockIdx.x;
    const int tid = threadIdx.x;
    const int l   = tid & 63;
    const int cp  = tid >> 6;
    __shared__ float smp[512];
    __shared__ float spart[256];
    __shared__ float satt[64], sexp[64], ssm[64];
    __shared__ float red[256];

    const float* o2b = o2 + (size_t)b*32768;

    // fused mp1: smp[d] = max_l o1[l,b,d]
#pragma unroll
    for (int h = 0; h < 2; ++h) {
        const int d = tid + h*256;
        float m = -3.402823466e+38f;
        for (int ll = 0; ll < 64; ++ll)
            m = fmaxf(m, o1[(size_t)ll*(NB*DDIM) + b*DDIM + d]);
        smp[d] = m;
    }
    __syncthreads();

    float p = 0.0f;
    for (int d = cp*128; d < cp*128 + 128; ++d)
        p += smp[d] * o2b[d*64 + l];
    spart[tid] = p;
    __syncthreads();
    if (tid < 64)
        satt[tid] = spart[tid] + spart[tid+64] + spart[tid+128] + spart[tid+192];
    __syncthreads();
    if (tid < 64) {
        float mx = satt[0];
        for (int i = 1; i < 64; ++i) mx = fmaxf(mx, satt[i]);
        sexp[tid] = expf(satt[tid] - mx);
    }
    __syncthreads();
    if (tid < 64) {
        float s = 0.0f;
        for (int i = 0; i < 64; ++i) s += sexp[i];
        ssm[tid] = sexp[tid] / s;
    }
    __syncthreads();

    float np0 = 0.0f, np1 = 0.0f;
    for (int l2 = 0; l2 < 64; ++l2) {
        float smv = ssm[l2];
        np0 += smv * o2b[l2*DDIM + tid];
        np1 += smv * o2b[l2*DDIM + tid + 256];
    }
    float diff = fabsf(smp[tid] - np0) + fabsf(smp[tid+256] - np1);
    red[tid] = diff;
    __syncthreads();
    for (int s = 128; s > 0; s >>= 1) {
        if (tid < s) red[tid] += red[tid + s];
        __syncthreads();
    }
    if (tid == 0) sim[b] = expf(-red[0]);
}

// ---------------------------------------------------------------------------
// commonWords + masked maxes (unchanged)
// ---------------------------------------------------------------------------
__global__ __launch_bounds__(256) void k_common(
    const int*   __restrict__ t1, const int* __restrict__ t2,
    const float* __restrict__ o1, const float* __restrict__ o2,
    float* __restrict__ e1h, float* __restrict__ e2h)
{
    const int b   = blockIdx.x;
    const int tid = threadIdx.x;
    __shared__ int ss1[64];
    __shared__ int smask[64];
    __shared__ int spos[64];
    __shared__ int sany;
    if (tid == 0) sany = 0;
    if (tid < 64) ss1[tid] = t1[tid*NB + b];
    __syncthreads();
    if (tid < 64) {
        int s2 = t2[tid*NB + b];
        int dmax = -1;
        for (int j = 0; j < 64; ++j)
            if (ss1[j] == s2) dmax = j;
        int mk = (dmax > 1) && (s2 > 0);
        smask[tid] = mk;
        spos[tid]  = dmax < 0 ? 0 : dmax;
        if (mk) sany = 1;
    }
    __syncthreads();
    int has = sany;
#pragma unroll
    for (int half = 0; half < 2; ++half) {
        int dd = tid + half*256;
        float m1 = -3.402823466e+38f, m2 = -3.402823466e+38f;
        for (int i = 0; i < 64; ++i) {
            if (smask[i]) {
                m1 = fmaxf(m1, o1[(size_t)spos[i]*(NB*DDIM) + b*DDIM + dd]);
                m2 = fmaxf(m2, o2[(size_t)i      *(NB*DDIM) + b*DDIM + dd]);
            }
        }
        e1h[b*DDIM + dd] = has ? m1 : 0.0f;
        e2h[b*DDIM + dd] = has ? m2 : 0.0f;
    }
}

// ---------------------------------------------------------------------------
extern "C" void kernel_launch(void* const* d_in, const int* in_sizes, int n_in,
                              void* d_out, int out_size, void* d_ws, size_t ws_size,
                              hipStream_t stream)
{
    (void)in_sizes; (void)n_in; (void)out_size; (void)ws_size;
    const int*   t1    = (const int*)d_in[0];
    const int*   t2    = (const int*)d_in[1];
    const float* emb   = (const float*)d_in[2];
    const float* wih_f = (const float*)d_in[3];
    const float* whh_f = (const float*)d_in[4];
    const float* bih_f = (const float*)d_in[5];
    const float* bhh_f = (const float*)d_in[6];
    const float* wih_b = (const float*)d_in[7];
    const float* whh_b = (const float*)d_in[8];
    const float* bih_b = (const float*)d_in[9];
    const float* bhh_b = (const float*)d_in[10];
    float* out = (float*)d_out;

    char* ws = (char*)d_ws;
    size_t off = 0;
    auto carve = [&](size_t bytes) -> void* {
        void* p = ws + off;
        off = (off + bytes + 255) & ~(size_t)255;
        return p;
    };
    float*  o1    = (float*)carve(sizeof(float)*(size_t)L_SEQ*NB*DDIM);
    float*  o2    = (float*)carve(sizeof(float)*(size_t)L_SEQ*NB*DDIM);
    bf16_t* whhB  = (bf16_t*)carve(sizeof(bf16_t)*2*1024*HID);
    bf16_t* Bw    = (bf16_t*)carve(sizeof(bf16_t)*(size_t)NCOL*EMBD);
    float*  bias  = (float*)carve(sizeof(float)*NCOL);
    bf16_t* xgT   = (bf16_t*)carve(sizeof(bf16_t)*(size_t)MTOT*NCOL);  // 67 MB

    hipFuncSetAttribute((const void*)lstm_scan8,
                        hipFuncAttributeMaxDynamicSharedMemorySize, 147456);
    hipFuncSetAttribute((const void*)k_embgemm,
                        hipFuncAttributeMaxDynamicSharedMemorySize, 98304);

    hipLaunchKernelGGL(k_pack_w, dim3(776), dim3(256), 0, stream,
                       wih_f, wih_b, whh_f, whh_b,
                       bih_f, bhh_f, bih_b, bhh_b, Bw, whhB, bias);

    hipLaunchKernelGGL(k_embgemm, dim3(256), dim3(512), 98304, stream,
                       t1, t2, emb, Bw, bias, xgT);

    hipLaunchKernelGGL(lstm_scan8, dim3(8, 4), dim3(1024), 147456, stream,
                       whhB, xgT, o1, o2);

    hipLaunchKernelGGL(k_att,    dim3(128), dim3(256), 0, stream, o1, o2, out);
    hipLaunchKernelGGL(k_common, dim3(128), dim3(256), 0, stream,
                       t1, t2, o1, o2, out + NB, out + NB + NB*DDIM);
}

// Round 5
// 614.535 us; speedup vs baseline: 1.0514x; 1.0514x over previous
//
#include <hip/hip_runtime.h>
#include <hip/hip_bf16.h>
#include <math.h>

#define L_SEQ 64
#define NB    128
#define EMBD  512
#define HID   256
#define G4    1024      // 4*HID
#define NCOL  2048      // 2 dirs * 4H
#define DDIM  512       // 2*HID
#define MS    (L_SEQ*NB)   // 8192 rows per sentence
#define MTOT  (2*MS)       // 16384 combined rows

typedef __bf16 bf16_t;
typedef bf16_t bf16x4 __attribute__((ext_vector_type(4)));
typedef bf16_t bf16x8 __attribute__((ext_vector_type(8)));
typedef float  floatx4 __attribute__((ext_vector_type(4)));
typedef float  floatx8 __attribute__((ext_vector_type(8)));

__device__ __forceinline__ bf16x8 cvt_bf16x8(floatx8 v) {
    bf16x8 r;
    r[0]=(bf16_t)v[0]; r[1]=(bf16_t)v[1]; r[2]=(bf16_t)v[2]; r[3]=(bf16_t)v[3];
    r[4]=(bf16_t)v[4]; r[5]=(bf16_t)v[5]; r[6]=(bf16_t)v[6]; r[7]=(bf16_t)v[7];
    return r;
}

__device__ __forceinline__ void gload_lds16(const bf16_t* g, bf16_t* l) {
    __builtin_amdgcn_global_load_lds(
        (const __attribute__((address_space(1))) unsigned int*)(g),
        (__attribute__((address_space(3))) unsigned int*)(l), 16, 0, 0);
}

__device__ __forceinline__ float fsigmoid(float x) {
    return __builtin_amdgcn_rcpf(1.0f + __expf(-x));
}
__device__ __forceinline__ float ftanh(float x) {
    return 1.0f - 2.0f * __builtin_amdgcn_rcpf(__expf(2.0f*x) + 1.0f);
}

// Raw workgroup barrier: drain LDS ops only (h ping-pong visibility), skip the
// vmcnt(0) store-ack drain __syncthreads would force.
#define LDS_BARRIER() asm volatile("s_waitcnt lgkmcnt(0)\n\ts_barrier" ::: "memory")

// ---------------------------------------------------------------------------
// Pack kernels
// ---------------------------------------------------------------------------
__global__ __launch_bounds__(256) void k_pack_a(const int* __restrict__ t1,
                                                const int* __restrict__ t2,
                                                const float* __restrict__ emb,
                                                bf16_t* __restrict__ A)
{
    int gid = blockIdx.x*256 + threadIdx.x;
    int row = gid >> 6;
    int k8  = (gid & 63) * 8;
    int tok = (row < MS) ? t1[row] : t2[row - MS];
    floatx8 v = *(const floatx8*)(emb + (size_t)tok*EMBD + k8);
    *(bf16x8*)(A + (size_t)row*EMBD + k8) = cvt_bf16x8(v);
}

__global__ __launch_bounds__(256) void k_pack_w(
    const float* __restrict__ wih_f, const float* __restrict__ wih_b,
    const float* __restrict__ whh_f, const float* __restrict__ whh_b,
    const float* __restrict__ bih_f, const float* __restrict__ bhh_f,
    const float* __restrict__ bih_b, const float* __restrict__ bhh_b,
    bf16_t* __restrict__ B, bf16_t* __restrict__ whhB,
    float* __restrict__ bias)
{
    int gid = blockIdx.x*256 + threadIdx.x;
    if (gid < 131072) {                       // wih pack: 2048 rows x 8 vec8
        int n  = gid >> 6;
        int k8 = (gid & 63) * 8;
        const float* src = (n >= 1024) ? (wih_b + (size_t)(n-1024)*EMBD)
                                       : (wih_f + (size_t)n*EMBD);
        *(bf16x8*)(B + (size_t)n*EMBD + k8) = cvt_bf16x8(*(const floatx8*)(src + k8));
    } else if (gid < 196608) {                // whh pack: 2048 rows x 4 vec8
        int g2 = gid - 131072;
        int r2 = g2 >> 5;
        int k8 = (g2 & 31) * 8;
        const float* src = (r2 >= 1024) ? (whh_b + (size_t)(r2-1024)*HID)
                                        : (whh_f + (size_t)r2*HID);
        *(bf16x8*)(whhB + (size_t)r2*HID + k8) = cvt_bf16x8(*(const floatx8*)(src + k8));
    } else {                                  // bias: 2048 scalars
        int n = gid - 196608;
        bias[n] = (n >= 1024) ? (bih_b[n-1024] + bhh_b[n-1024])
                              : (bih_f[n] + bhh_f[n]);
    }
}

// ---------------------------------------------------------------------------
// xg GEMM v4 (R1 form, no swizzle — R3 proved swizzle = 0 delta).
//  Epilogue stores bf16 per-chunk layout:
//   xgT[(((s2*8 + ch)*64 + l)*1024 + gcol)*16 + bi],  ch=b>>4, bi=b&15
// ---------------------------------------------------------------------------
__global__ __launch_bounds__(256) void xg_gemm4(const bf16_t* __restrict__ A,
                                                const bf16_t* __restrict__ B,
                                                const float* __restrict__ bias,
                                                bf16_t* __restrict__ xgT)
{
    __shared__ bf16_t As[128*32];
    __shared__ bf16_t Bs[128*32];
    const int tid  = threadIdx.x;
    const int wid  = tid >> 6;
    const int lane = tid & 63;
    const int l15  = lane & 15;
    const int quad = lane >> 4;
    const int m0   = blockIdx.y * 128;
    const int n0   = blockIdx.x * 128;
    const int mw   = (wid & 1) * 64;
    const int nw   = (wid >> 1) * 64;

    float biasv[4];
#pragma unroll
    for (int ni = 0; ni < 4; ++ni) biasv[ni] = bias[n0 + nw + ni*16 + l15];

    const int srow = tid >> 2;
    const int sk8  = (tid & 3) * 8;

    floatx4 acc[4][4] = {};
    for (int kk = 0; kk < EMBD; kk += 32) {
#pragma unroll
        for (int inst = 0; inst < 2; ++inst) {
            gload_lds16(A + (size_t)(m0 + inst*64 + srow)*EMBD + kk + sk8,
                        As + inst*2048 + wid*512);
            gload_lds16(B + (size_t)(n0 + inst*64 + srow)*EMBD + kk + sk8,
                        Bs + inst*2048 + wid*512);
        }
        __syncthreads();
        bf16x8 a[4], b[4];
#pragma unroll
        for (int mi = 0; mi < 4; ++mi)
            a[mi] = *(const bf16x8*)(As + (mw + mi*16 + l15)*32 + quad*8);
#pragma unroll
        for (int ni = 0; ni < 4; ++ni)
            b[ni] = *(const bf16x8*)(Bs + (nw + ni*16 + l15)*32 + quad*8);
#pragma unroll
        for (int mi = 0; mi < 4; ++mi)
#pragma unroll
            for (int ni = 0; ni < 4; ++ni)
                acc[mi][ni] = __builtin_amdgcn_mfma_f32_16x16x32_bf16(
                                  a[mi], b[ni], acc[mi][ni], 0, 0, 0);
        __syncthreads();
    }

    // epilogue: per-chunk transposed bf16 store
    const int sent = blockIdx.y >> 6;       // m = sent*8192 + l*128 + b
    const int l    = blockIdx.y & 63;
    const int dir  = n0 >> 10;              // uniform per block
    const int s2   = sent*2 + dir;
#pragma unroll
    for (int mi = 0; mi < 4; ++mi)
#pragma unroll
        for (int ni = 0; ni < 4; ++ni) {
            int gcol = (n0 & 1023) + nw + ni*16 + l15;
            int b    = mw + mi*16 + quad*4;
            int ch   = b >> 4;
            int bi   = b & 15;
            bf16x4 v;
#pragma unroll
            for (int r = 0; r < 4; ++r) v[r] = (bf16_t)(acc[mi][ni][r] + biasv[ni]);
            *(bf16x4*)(xgT + ((size_t)((s2*8 + ch)*64 + l)*1024 + gcol)*16 + bi) = v;
        }
}

// ---------------------------------------------------------------------------
// LSTM scan v10 = v8 + cross-step xg prefetch, register-neutral.
//  v8 analysis: step = 13.6k cyc; summed pipe work ~6.3k (46%); critical
//  path ~600 cyc. Remaining candidate: xg (L3/HBM, ~55% HBM miss) issued at
//  step top, consumed in the SAME step's epilogue -> in-step slack 2-4k cyc
//  < HBM tail; any straggler wave delays the 16-wave barrier every step.
//  v10: fold xg into acc at epilogue start (bitwise-identical adds, earlier),
//  killing xvc's live range; immediately reuse the SAME 8 VGPRs to issue
//  step t+1's xg -> a full step (~13.6k cyc) of slack, zero extra registers
//  (budget is exactly 64 VGPR + 64 AGPR = 128 at 4 waves/EU).
// ---------------------------------------------------------------------------
__global__
__attribute__((amdgpu_flat_work_group_size(1024, 1024), amdgpu_waves_per_eu(4, 4)))
void lstm_scan10(
    const bf16_t* __restrict__ whhB,   // [2][1024][256] bf16
    const bf16_t* __restrict__ xgT,    // per-chunk layout
    float* __restrict__ o1, float* __restrict__ o2)
{
    extern __shared__ char smem[];
    bf16_t* hb = (bf16_t*)smem;              // 2 frames x 4096 bf16 = 16 KB
    bf16_t* BL = (bf16_t*)(smem + 16384);    // 128 frags x 512 bf16 = 128 KB

    const int tid  = threadIdx.x;
    const int wv   = tid >> 6;            // 0..15
    const int lane = tid & 63;
    const int l15  = lane & 15;
    const int quad = lane >> 4;
    const int s2   = blockIdx.y;          // sent*2 + dr
    const int sent = s2 >> 1;
    const int dr   = s2 & 1;
    const int chunk= blockIdx.x;
    const int b0   = chunk * 16;
    float* o = sent ? o2 : o1;
    const bf16_t* bb = whhB + (size_t)dr * (1024*HID);
    const bf16_t* xbase = xgT + (size_t)((s2*8 + chunk)*64)*16384;

    // wave wv owns units j = wv*16 + l15; gate column col(g) = g*256 + wv*16 + l15

    // ---- LDS weight preload: ks 4,5 for all 4 gates of this wave's unit slice
#pragma unroll
    for (int g = 0; g < 4; ++g) {
        const int col = g*256 + wv*16 + l15;
#pragma unroll
        for (int ksl = 0; ksl < 2; ++ksl)
            gload_lds16(bb + (size_t)col*HID + (4+ksl)*32 + quad*8,
                        BL + (size_t)((wv*4 + g)*2 + ksl)*512);
    }

    // ---- VGPR weights ks0..3 — volatile loads: no rematerialization
    bf16x8 bwc[4][4];
#pragma unroll
    for (int g = 0; g < 4; ++g) {
        const bf16_t* cp = bb + (size_t)(g*256 + wv*16 + l15)*HID + quad*8;
#pragma unroll
        for (int ks = 0; ks < 4; ++ks)
            bwc[g][ks] = *(const volatile bf16x8*)(cp + ks*32);
    }

    // zero h frame 0 (legacy safety; frame 0 is never read before first write)
    for (int i = tid; i < 4096; i += 1024) hb[i] = (bf16_t)0.0f;
    __syncthreads();   // full drain once (also covers global_load_lds)

    float cst[4] = {};
    int pp = 0;

    // prologue: xg for step 0
    bf16x4 xvc[4];
    {
        const int lt0 = dr ? (L_SEQ-1) : 0;
        const bf16_t* xp = xbase + (size_t)lt0*16384;
#pragma unroll
        for (int g = 0; g < 4; ++g)
            xvc[g] = *(const bf16x4*)(xp + (size_t)(g*256 + wv*16 + l15)*16
                                      + quad*4);
    }

    for (int t = 0; t < L_SEQ; ++t) {
        const int lt = dr ? (L_SEQ-1-t) : t;
        asm volatile("" ::: "memory");   // keep in-loop loads in-loop

        floatx4 acc[4] = {};
        if (t > 0) {
            // streamed weight buffer (single 16-reg buffer, used twice)
            bf16x8 sb[4];
#pragma unroll
            for (int g = 0; g < 4; ++g) {
                const bf16_t* cp = bb + (size_t)(g*256 + wv*16 + l15)*HID;
                sb[g] = *(const bf16x8*)(cp + 6*32 + quad*8);
            }

            const bf16_t* fr = hb + pp*4096;
            // ks0..3: VGPR weights
#pragma unroll
            for (int ks = 0; ks < 4; ++ks) {
                bf16x8 af = *(const bf16x8*)(fr + ((ks*4 + quad)*16 + l15)*8);
#pragma unroll
                for (int g = 0; g < 4; ++g)
                    acc[g] = __builtin_amdgcn_mfma_f32_16x16x32_bf16(
                                 af, bwc[g][ks], acc[g], 0, 0, 0);
            }
            // ks6: streamed batch 1
            {
                bf16x8 af6 = *(const bf16x8*)(fr + ((6*4 + quad)*16 + l15)*8);
#pragma unroll
                for (int g = 0; g < 4; ++g)
                    acc[g] = __builtin_amdgcn_mfma_f32_16x16x32_bf16(
                                 af6, sb[g], acc[g], 0, 0, 0);
            }
            // reissue stream buffer for ks7; ks4,5 (LDS) hide its L2 latency
#pragma unroll
            for (int g = 0; g < 4; ++g) {
                const bf16_t* cp = bb + (size_t)(g*256 + wv*16 + l15)*HID;
                sb[g] = *(const bf16x8*)(cp + 7*32 + quad*8);
            }
            // ks4,5: LDS weights
#pragma unroll
            for (int ksl = 0; ksl < 2; ++ksl) {
                bf16x8 af = *(const bf16x8*)(fr + (((4+ksl)*4 + quad)*16 + l15)*8);
#pragma unroll
                for (int g = 0; g < 4; ++g) {
                    bf16x8 bl = *(const bf16x8*)(BL + (size_t)((wv*4 + g)*2 + ksl)*512
                                                 + lane*8);
                    acc[g] = __builtin_amdgcn_mfma_f32_16x16x32_bf16(
                                 af, bl, acc[g], 0, 0, 0);
                }
            }
            // ks7: streamed batch 2
            {
                bf16x8 af7 = *(const bf16x8*)(fr + ((7*4 + quad)*16 + l15)*8);
#pragma unroll
                for (int g = 0; g < 4; ++g)
                    acc[g] = __builtin_amdgcn_mfma_f32_16x16x32_bf16(
                                 af7, sb[g], acc[g], 0, 0, 0);
            }
        }

        // ---- fold xg into acc NOW (bitwise-identical adds, moved earlier;
        //      at t==0 acc is exact zero, so acc+xg == old gi/gf/gg/go)
#pragma unroll
        for (int g = 0; g < 4; ++g)
#pragma unroll
            for (int r = 0; r < 4; ++r)
                acc[g][r] += (float)xvc[g][r];

        // ---- xvc dead: reuse its registers to issue NEXT step's xg —
        //      a full step of slack covers even HBM-miss latency
        {
            const int tn  = (t < L_SEQ-1) ? t+1 : t;   // t=63: harmless reload
            const int ltn = dr ? (L_SEQ-1-tn) : tn;
            const bf16_t* xp = xbase + (size_t)ltn*16384;
#pragma unroll
            for (int g = 0; g < 4; ++g)
                xvc[g] = *(const bf16x4*)(xp + (size_t)(g*256 + wv*16 + l15)*16
                                          + quad*4);
        }

        // epilogue: rows m = quad*4+r, unit j = wv*16 + l15
        bf16_t* fw = hb + (pp^1)*4096;
        const int j = wv*16 + l15;
        float* orow = o + (size_t)(lt*NB + b0)*DDIM + dr*HID + j;
#pragma unroll
        for (int r = 0; r < 4; ++r) {
            const int m = quad*4 + r;
            float cv = fsigmoid(acc[1][r])*cst[r] + fsigmoid(acc[0][r])*ftanh(acc[2][r]);
            cst[r] = cv;
            float hv = fsigmoid(acc[3][r])*ftanh(cv);
            orow[(size_t)m*DDIM] = hv;
            fw[((j >> 3)*16 + m)*8 + (j & 7)] = (bf16_t)hv;
        }
        LDS_BARRIER();
        pp ^= 1;
    }
}

// ---------------------------------------------------------------------------
// attention + sim with fused mp1 (unchanged from R3)
// ---------------------------------------------------------------------------
__global__ __launch_bounds__(256) void k_att(const float* __restrict__ o1,
                                             const float* __restrict__ o2,
                                             float* __restrict__ sim)
{
    const int b   = blockIdx.x;
    const int tid = threadIdx.x;
    const int l   = tid & 63;
    const int cp  = tid >> 6;
    __shared__ float smp[512];
    __shared__ float spart[256];
    __shared__ float satt[64], sexp[64], ssm[64];
    __shared__ float red[256];

    const float* o2b = o2 + (size_t)b*32768;

    // fused mp1: smp[d] = max_l o1[l,b,d]
#pragma unroll
    for (int h = 0; h < 2; ++h) {
        const int d = tid + h*256;
        float m = -3.402823466e+38f;
        for (int ll = 0; ll < 64; ++ll)
            m = fmaxf(m, o1[(size_t)ll*(NB*DDIM) + b*DDIM + d]);
        smp[d] = m;
    }
    __syncthreads();

    float p = 0.0f;
    for (int d = cp*128; d < cp*128 + 128; ++d)
        p += smp[d] * o2b[d*64 + l];
    spart[tid] = p;
    __syncthreads();
    if (tid < 64)
        satt[tid] = spart[tid] + spart[tid+64] + spart[tid+128] + spart[tid+192];
    __syncthreads();
    if (tid < 64) {
        float mx = satt[0];
        for (int i = 1; i < 64; ++i) mx = fmaxf(mx, satt[i]);
        sexp[tid] = expf(satt[tid] - mx);
    }
    __syncthreads();
    if (tid < 64) {
        float s = 0.0f;
        for (int i = 0; i < 64; ++i) s += sexp[i];
        ssm[tid] = sexp[tid] / s;
    }
    __syncthreads();

    float np0 = 0.0f, np1 = 0.0f;
    for (int l2 = 0; l2 < 64; ++l2) {
        float smv = ssm[l2];
        np0 += smv * o2b[l2*DDIM + tid];
        np1 += smv * o2b[l2*DDIM + tid + 256];
    }
    float diff = fabsf(smp[tid] - np0) + fabsf(smp[tid+256] - np1);
    red[tid] = diff;
    __syncthreads();
    for (int s = 128; s > 0; s >>= 1) {
        if (tid < s) red[tid] += red[tid + s];
        __syncthreads();
    }
    if (tid == 0) sim[b] = expf(-red[0]);
}

// ---------------------------------------------------------------------------
// commonWords + masked maxes (unchanged)
// ---------------------------------------------------------------------------
__global__ __launch_bounds__(256) void k_common(
    const int*   __restrict__ t1, const int* __restrict__ t2,
    const float* __restrict__ o1, const float* __restrict__ o2,
    float* __restrict__ e1h, float* __restrict__ e2h)
{
    const int b   = blockIdx.x;
    const int tid = threadIdx.x;
    __shared__ int ss1[64];
    __shared__ int smask[64];
    __shared__ int spos[64];
    __shared__ int sany;
    if (tid == 0) sany = 0;
    if (tid < 64) ss1[tid] = t1[tid*NB + b];
    __syncthreads();
    if (tid < 64) {
        int s2 = t2[tid*NB + b];
        int dmax = -1;
        for (int j = 0; j < 64; ++j)
            if (ss1[j] == s2) dmax = j;
        int mk = (dmax > 1) && (s2 > 0);
        smask[tid] = mk;
        spos[tid]  = dmax < 0 ? 0 : dmax;
        if (mk) sany = 1;
    }
    __syncthreads();
    int has = sany;
#pragma unroll
    for (int half = 0; half < 2; ++half) {
        int dd = tid + half*256;
        float m1 = -3.402823466e+38f, m2 = -3.402823466e+38f;
        for (int i = 0; i < 64; ++i) {
            if (smask[i]) {
                m1 = fmaxf(m1, o1[(size_t)spos[i]*(NB*DDIM) + b*DDIM + dd]);
                m2 = fmaxf(m2, o2[(size_t)i      *(NB*DDIM) + b*DDIM + dd]);
            }
        }
        e1h[b*DDIM + dd] = has ? m1 : 0.0f;
        e2h[b*DDIM + dd] = has ? m2 : 0.0f;
    }
}

// ---------------------------------------------------------------------------
extern "C" void kernel_launch(void* const* d_in, const int* in_sizes, int n_in,
                              void* d_out, int out_size, void* d_ws, size_t ws_size,
                              hipStream_t stream)
{
    (void)in_sizes; (void)n_in; (void)out_size; (void)ws_size;
    const int*   t1    = (const int*)d_in[0];
    const int*   t2    = (const int*)d_in[1];
    const float* emb   = (const float*)d_in[2];
    const float* wih_f = (const float*)d_in[3];
    const float* whh_f = (const float*)d_in[4];
    const float* bih_f = (const float*)d_in[5];
    const float* bhh_f = (const float*)d_in[6];
    const float* wih_b = (const float*)d_in[7];
    const float* whh_b = (const float*)d_in[8];
    const float* bih_b = (const float*)d_in[9];
    const float* bhh_b = (const float*)d_in[10];
    float* out = (float*)d_out;

    char* ws = (char*)d_ws;
    size_t off = 0;
    auto carve = [&](size_t bytes) -> void* {
        void* p = ws + off;
        off = (off + bytes + 255) & ~(size_t)255;
        return p;
    };
    float*  o1    = (float*)carve(sizeof(float)*(size_t)L_SEQ*NB*DDIM);
    float*  o2    = (float*)carve(sizeof(float)*(size_t)L_SEQ*NB*DDIM);
    bf16_t* whhB  = (bf16_t*)carve(sizeof(bf16_t)*2*1024*HID);
    bf16_t* Bw    = (bf16_t*)carve(sizeof(bf16_t)*(size_t)NCOL*EMBD);
    float*  bias  = (float*)carve(sizeof(float)*NCOL);
    bf16_t* xgT   = (bf16_t*)carve(sizeof(bf16_t)*(size_t)MTOT*NCOL);  // 67 MB
    bf16_t* A     = (bf16_t*)o1;   // A dead before scan writes o1

    hipFuncSetAttribute((const void*)lstm_scan10,
                        hipFuncAttributeMaxDynamicSharedMemorySize, 147456);

    hipLaunchKernelGGL(k_pack_a, dim3(4096), dim3(256), 0, stream, t1, t2, emb, A);
    hipLaunchKernelGGL(k_pack_w, dim3(776),  dim3(256), 0, stream,
                       wih_f, wih_b, whh_f, whh_b,
                       bih_f, bhh_f, bih_b, bhh_b, Bw, whhB, bias);

    hipLaunchKernelGGL(xg_gemm4, dim3(16, 128), dim3(256), 0, stream, A, Bw, bias, xgT);

    hipLaunchKernelGGL(lstm_scan10, dim3(8, 4), dim3(1024), 147456, stream,
                       whhB, xgT, o1, o2);

    hipLaunchKernelGGL(k_att,    dim3(128), dim3(256), 0, stream, o1, o2, out);
    hipLaunchKernelGGL(k_common, dim3(128), dim3(256), 0, stream,
                       t1, t2, o1, o2, out + NB, out + NB + NB*DDIM);
}